// Round 7
// baseline (145.578 us; speedup 1.0000x reference)
//
#include <hip/hip_runtime.h>

// APLoss (r2d2 QAPLoss). B=2, H=W=32 -> N=M=1024/batch, D=128, 25 bins.
// u = 24*(1-sim); cumsum_k of triangular bins = clamp(k+1-u, 0, 1).
// 3 kernels: grid-sample -> fused sim+hist (block = 8q x 512m, c-split teams,
// label prefetch) -> AP+final reduce.

#define NQB 25

// DPP butterfly add over 16-lane rows (pure VALU, no LDS pipe).
template<int CTRL>
__device__ __forceinline__ float dppadd(float v) {
    int s = __builtin_amdgcn_update_dpp(0, __float_as_int(v), CTRL, 0xf, 0xf, true);
    return v + __int_as_float(s);
}
__device__ __forceinline__ float red16(float v) {
    v = dppadd<0xB1>(v);   // quad_perm xor1
    v = dppadd<0x4E>(v);   // quad_perm xor2
    v = dppadd<0x141>(v);  // row_half_mirror = xor7
    v = dppadd<0x140>(v);  // row_mirror      = xor15
    return v;              // every lane: its 16-lane-row sum
}

// ---- K1: bilinear grid-sample desc2 -> dbt[b][c][m]; block = (b,c) ---------
__global__ __launch_bounds__(256) void k_gs(const float* __restrict__ desc2,
                                            const float* __restrict__ grd,
                                            float* __restrict__ dbt)
{
    __shared__ float plane[1024];
    int r = blockIdx.x;            // b*128 + c
    int b = r >> 7;
    int tid = threadIdx.x;
    const float* src = desc2 + ((size_t)r << 10);
    *(float4*)&plane[tid * 4] = *(const float4*)&src[tid * 4];
    __syncthreads();
#pragma unroll
    for (int e = 0; e < 4; e++) {
        int m = tid + (e << 8);
        int pos = (b << 10) + m;
        float2 g = ((const float2*)grd)[pos];
        float fx = ((g.x + 1.f) * 32.f - 1.f) * 0.5f;
        float fy = ((g.y + 1.f) * 32.f - 1.f) * 0.5f;
        float x0f = floorf(fx), y0f = floorf(fy);
        float wx1 = fx - x0f, wy1 = fy - y0f;
        float wx0 = 1.f - wx1, wy0 = 1.f - wy1;
        int x0 = (int)x0f, y0 = (int)y0f;
        float acc = 0.f;
        if ((unsigned)y0 < 32u && (unsigned)x0 < 32u)
            acc += wy0 * wx0 * plane[(y0 << 5) + x0];
        if ((unsigned)y0 < 32u && (unsigned)(x0 + 1) < 32u)
            acc += wy0 * wx1 * plane[(y0 << 5) + x0 + 1];
        if ((unsigned)(y0 + 1) < 32u && (unsigned)x0 < 32u)
            acc += wy1 * wx0 * plane[((y0 + 1) << 5) + x0];
        if ((unsigned)(y0 + 1) < 32u && (unsigned)(x0 + 1) < 32u)
            acc += wy1 * wx1 * plane[((y0 + 1) << 5) + x0 + 1];
        dbt[((size_t)r << 10) + m] = acc;
    }
}

// ---- K2: fused sim + histogram; block = 8 q x 512 m, 1024 thr (16 waves) ---
// Sim: c-teams (waves 0-7: c 0..63 -> sA; waves 8-15: c 64..127 -> sB),
// thread owns one local m. Hist: 2 waves/query (m-quarters h), lane l owns
// m = h*256 + l + 64e, labels prefetched pre-sim. Output: bin-major partials
// P[(mh*50 + j)*npos + qg], j<25 = CN_j, j-25 = CR_j.
__global__ __launch_bounds__(1024, 8) void k_main(const float* __restrict__ desc1,
                                                  const float* __restrict__ dbt,
                                                  const int* __restrict__ label,
                                                  float* __restrict__ partials,
                                                  int npos)
{
    __shared__ float sA[8][512];
    __shared__ float sB[8][512];
    __shared__ float CNs[8][8][NQB];
    __shared__ float CRs[8][8][NQB];

    int tid = threadIdx.x;
    int bid = blockIdx.x;
    int qg0 = (bid >> 1) << 3;      // query-group base (b*1024 + n0)
    int b = qg0 >> 10;
    int n0 = qg0 & 1023;
    int m0 = (bid & 1) << 9;        // m-half base within batch

    // hist role + label prefetch (HBM latency hides under sim phase)
    int w = tid >> 6, l = tid & 63;
    int q = w >> 1, h = w & 1;
    const int* lp = label + ((size_t)(qg0 + q) << 10) + m0 + (h << 8) + l;
    float lf0 = (float)lp[0];
    float lf1 = (float)lp[64];
    float lf2 = (float)lp[128];
    float lf3 = (float)lp[192];

    // sim role: team 0 -> c 0..63 -> sA; team 1 -> c 64..127 -> sB
    int team = tid >> 9;
    int mloc = tid & 511;
    int cbase = team << 6;
    const float* dp = dbt + ((size_t)b << 17) + m0 + mloc;
    const float* d1 = desc1 + ((size_t)b << 17) + n0;  // q-row: d1[(c<<10)+qq]

    float a[8];
#pragma unroll
    for (int qq = 0; qq < 8; qq++) a[qq] = 0.f;

#pragma unroll 2
    for (int cc = 0; cc < 64; cc += 4) {
        int c = cbase + cc;
        float d0 = dp[(size_t)(c + 0) << 10];
        float d1v = dp[(size_t)(c + 1) << 10];
        float d2 = dp[(size_t)(c + 2) << 10];
        float d3 = dp[(size_t)(c + 3) << 10];
#pragma unroll
        for (int qq = 0; qq < 8; qq++) {
            // wave-uniform scalar loads (8 consecutive floats per channel row)
            float qa = d1[((size_t)(c + 0) << 10) + qq];
            float qb = d1[((size_t)(c + 1) << 10) + qq];
            float qc = d1[((size_t)(c + 2) << 10) + qq];
            float qd = d1[((size_t)(c + 3) << 10) + qq];
            a[qq] = fmaf(qa, d0, fmaf(qb, d1v, fmaf(qc, d2, fmaf(qd, d3, a[qq]))));
        }
    }
    {
        float (*sT)[512] = team ? sB : sA;
#pragma unroll
        for (int qq = 0; qq < 8; qq++) sT[qq][mloc] = a[qq];
    }
    __syncthreads();

    // histogram: sv = sA + sB (combines c-teams); conflict-free lane-stride-1
    float CN[NQB], CR[NQB];
#pragma unroll
    for (int k = 0; k < NQB; k++) { CN[k] = 0.f; CR[k] = 0.f; }
    const float* spA = &sA[q][(h << 8) + l];
    const float* spB = &sB[q][(h << 8) + l];
    float lfs[4] = {lf0, lf1, lf2, lf3};
#pragma unroll
    for (int e = 0; e < 4; e++) {
        float sv = spA[e << 6] + spB[e << 6];
        float lfv = lfs[e];
        float u = fmaf(-24.f, sv, 24.f);
#pragma unroll
        for (int k = 0; k < NQB; k++) {
            float t = fminf(fmaxf((float)(k + 1) - u, 0.f), 1.f);  // v_med3
            CN[k] += t;
            CR[k] = fmaf(lfv, t, CR[k]);
        }
    }
#pragma unroll
    for (int k = 0; k < NQB; k++) { CN[k] = red16(CN[k]); CR[k] = red16(CR[k]); }
    if ((l & 15) == 0) {
        int rec = (h << 2) + (l >> 4);
#pragma unroll
        for (int k = 0; k < NQB; k++) { CNs[q][rec][k] = CN[k]; CRs[q][rec][k] = CR[k]; }
    }
    __syncthreads();

    // reduce 8 records/query -> bin-major global partials
    if (tid < 512) {
        int qq = tid >> 6, j = tid & 63;
        if (j < 50) {
            float vA = 0.f, vB = 0.f;
            int k = (j < 25) ? j : (j - 25);
#pragma unroll
            for (int rr = 0; rr < 8; rr++) { vA += CNs[qq][rr][k]; vB += CRs[qq][rr][k]; }
            float v = (j < 25) ? vA : vB;
            partials[(size_t)((bid & 1) * 50 + j) * npos + qg0 + qq] = v;
        }
    }
}

// ---- K3: per-query AP + global mean -> d_out -------------------------------
__global__ __launch_bounds__(1024) void k_apfinal(const float* __restrict__ partials,
                                                  float* __restrict__ out,
                                                  int npos, float invn)
{
    int tid = threadIdx.x;
    float apsum = 0.f;
    for (int qg = tid; qg < npos; qg += 1024) {
        float ap = 0.f, prev = 0.f;
#pragma unroll
        for (int k = 0; k < NQB; k++) {
            float cn = partials[(size_t)k * npos + qg] + partials[(size_t)(50 + k) * npos + qg];
            float cr = partials[(size_t)(25 + k) * npos + qg] + partials[(size_t)(75 + k) * npos + qg];
            float pr = cr / (1e-16f + cn);
            ap += pr * (cr - prev);
            prev = cr;
        }
        apsum += ap / prev;
    }
    for (int off = 32; off; off >>= 1) apsum += __shfl_xor(apsum, off, 64);
    __shared__ float wsum[16];
    if ((tid & 63) == 0) wsum[tid >> 6] = apsum;
    __syncthreads();
    if (tid == 0) {
        float v = 0.f;
#pragma unroll
        for (int i = 0; i < 16; i++) v += wsum[i];
        out[0] = v * invn;
    }
}

extern "C" void kernel_launch(void* const* d_in, const int* in_sizes, int n_in,
                              void* d_out, int out_size, void* d_ws, size_t ws_size,
                              hipStream_t stream)
{
    const float* desc1 = (const float*)d_in[0];
    const float* desc2 = (const float*)d_in[1];
    // d_in[2] = reliability: unused by the reference output
    const float* grd   = (const float*)d_in[3];
    const int*   label = (const int*)d_in[4];

    int B = in_sizes[0] / (128 * 1024);
    int npos = B * 1024;

    float* ws = (float*)d_ws;
    float* dbt      = ws;                          // npos*128 floats ([b][c][m])
    float* partials = dbt + (size_t)npos * 128;    // 100*npos floats (bin-major)
    float* out = (float*)d_out;

    k_gs<<<B * 128, 256, 0, stream>>>(desc2, grd, dbt);
    k_main<<<npos / 4, 1024, 0, stream>>>(desc1, dbt, label, partials, npos);
    k_apfinal<<<1, 1024, 0, stream>>>(partials, out, npos, 1.f / (float)npos);
}

// Round 8
// 33.769 us; speedup vs baseline: 4.3110x; 4.3110x over previous
//
#include <hip/hip_runtime.h>

// APLoss (r2d2 QAPLoss). B=2, H=W=32 -> N=M=1024/batch, D=128, 25 bins.
// u = 24*(1-sim); cumsum_k of triangular bins = clamp(k+1-u, 0, 1).
// 3 kernels: grid-sample -> fused sim+hist+AP -> reduce.
// k_main: block = 4 q x ALL 1024 m, 256 thr (4 waves), thread owns 4
// consecutive m (float4 dbt loads, 4x4 outer-product FMAs, scalar q-loads),
// labels prefetched to registers before sim. 512 blocks = 2 blocks/CU.

#define NQB 25

// DPP butterfly add over 16-lane rows (pure VALU, no LDS pipe).
template<int CTRL>
__device__ __forceinline__ float dppadd(float v) {
    int s = __builtin_amdgcn_update_dpp(0, __float_as_int(v), CTRL, 0xf, 0xf, true);
    return v + __int_as_float(s);
}
__device__ __forceinline__ float red16(float v) {
    v = dppadd<0xB1>(v);   // quad_perm xor1
    v = dppadd<0x4E>(v);   // quad_perm xor2
    v = dppadd<0x141>(v);  // row_half_mirror = xor7
    v = dppadd<0x140>(v);  // row_mirror      = xor15
    return v;              // every lane: its 16-lane-row sum
}

// ---- K1: bilinear grid-sample desc2 -> dbt[b][c][m]; block = (b,c) ---------
__global__ __launch_bounds__(256) void k_gs(const float* __restrict__ desc2,
                                            const float* __restrict__ grd,
                                            float* __restrict__ dbt)
{
    __shared__ float plane[1024];
    int r = blockIdx.x;            // b*128 + c
    int b = r >> 7;
    int tid = threadIdx.x;
    const float* src = desc2 + ((size_t)r << 10);
    *(float4*)&plane[tid * 4] = *(const float4*)&src[tid * 4];
    __syncthreads();
#pragma unroll
    for (int e = 0; e < 4; e++) {
        int m = tid + (e << 8);
        int pos = (b << 10) + m;
        float2 g = ((const float2*)grd)[pos];
        float fx = ((g.x + 1.f) * 32.f - 1.f) * 0.5f;
        float fy = ((g.y + 1.f) * 32.f - 1.f) * 0.5f;
        float x0f = floorf(fx), y0f = floorf(fy);
        float wx1 = fx - x0f, wy1 = fy - y0f;
        float wx0 = 1.f - wx1, wy0 = 1.f - wy1;
        int x0 = (int)x0f, y0 = (int)y0f;
        float acc = 0.f;
        if ((unsigned)y0 < 32u && (unsigned)x0 < 32u)
            acc += wy0 * wx0 * plane[(y0 << 5) + x0];
        if ((unsigned)y0 < 32u && (unsigned)(x0 + 1) < 32u)
            acc += wy0 * wx1 * plane[(y0 << 5) + x0 + 1];
        if ((unsigned)(y0 + 1) < 32u && (unsigned)x0 < 32u)
            acc += wy1 * wx0 * plane[((y0 + 1) << 5) + x0];
        if ((unsigned)(y0 + 1) < 32u && (unsigned)(x0 + 1) < 32u)
            acc += wy1 * wx1 * plane[((y0 + 1) << 5) + x0 + 1];
        dbt[((size_t)r << 10) + m] = acc;
    }
}

// ---- K2: fused sim + histogram + AP; block = 4 q x ALL 1024 m, 256 thr -----
__global__ __launch_bounds__(256) void k_main(const float* __restrict__ desc1,
                                              const float* __restrict__ dbt,
                                              const int* __restrict__ label,
                                              float* __restrict__ appart)
{
    __shared__ float s[4][1024];      // sim tile (16 KB)
    __shared__ float CNs[4][4][NQB];
    __shared__ float CRs[4][4][NQB];
    __shared__ float apb[4];

    int tid = threadIdx.x;
    int qg0 = blockIdx.x << 2;        // global query base (b*1024 + n0)
    int b = qg0 >> 10;
    int n0 = qg0 & 1023;

    // ---- label prefetch (registers; latency hides under sim phase) ----
    int q = tid >> 6, l = tid & 63;   // hist roles
    const int* lp = label + ((size_t)(qg0 + q) << 10) + l;
    float lf[16];
#pragma unroll
    for (int e = 0; e < 16; e++) lf[e] = (float)lp[(size_t)(e << 6)];

    // ---- sim phase: thread owns m = tid*4..+3 for all 4 q ----
    const float* dp = dbt + ((size_t)b << 17) + (tid << 2);
    const float* d1 = desc1 + ((size_t)b << 17) + n0;  // q-row: d1[(c<<10)+qq]

    float acc[4][4];
#pragma unroll
    for (int qq = 0; qq < 4; qq++)
#pragma unroll
        for (int j = 0; j < 4; j++) acc[qq][j] = 0.f;

#pragma unroll 4
    for (int c = 0; c < 128; c++) {
        float4 dv = *(const float4*)&dp[(size_t)c << 10];
        // wave-uniform scalar loads: 4 consecutive floats (s_load_dwordx4)
        float q0 = d1[((size_t)c << 10) + 0];
        float q1 = d1[((size_t)c << 10) + 1];
        float q2 = d1[((size_t)c << 10) + 2];
        float q3 = d1[((size_t)c << 10) + 3];
        acc[0][0] = fmaf(q0, dv.x, acc[0][0]); acc[0][1] = fmaf(q0, dv.y, acc[0][1]);
        acc[0][2] = fmaf(q0, dv.z, acc[0][2]); acc[0][3] = fmaf(q0, dv.w, acc[0][3]);
        acc[1][0] = fmaf(q1, dv.x, acc[1][0]); acc[1][1] = fmaf(q1, dv.y, acc[1][1]);
        acc[1][2] = fmaf(q1, dv.z, acc[1][2]); acc[1][3] = fmaf(q1, dv.w, acc[1][3]);
        acc[2][0] = fmaf(q2, dv.x, acc[2][0]); acc[2][1] = fmaf(q2, dv.y, acc[2][1]);
        acc[2][2] = fmaf(q2, dv.z, acc[2][2]); acc[2][3] = fmaf(q2, dv.w, acc[2][3]);
        acc[3][0] = fmaf(q3, dv.x, acc[3][0]); acc[3][1] = fmaf(q3, dv.y, acc[3][1]);
        acc[3][2] = fmaf(q3, dv.z, acc[3][2]); acc[3][3] = fmaf(q3, dv.w, acc[3][3]);
    }
#pragma unroll
    for (int qq = 0; qq < 4; qq++) {
        float4 v; v.x = acc[qq][0]; v.y = acc[qq][1]; v.z = acc[qq][2]; v.w = acc[qq][3];
        *(float4*)&s[qq][tid << 2] = v;
    }
    __syncthreads();

    // ---- histogram: wave = query, lane l owns m = l + 64e ----
    float CN[NQB], CR[NQB];
#pragma unroll
    for (int k = 0; k < NQB; k++) { CN[k] = 0.f; CR[k] = 0.f; }
#pragma unroll
    for (int e = 0; e < 16; e++) {
        float sv = s[q][l + (e << 6)];
        float u = fmaf(-24.f, sv, 24.f);
        float lfv = lf[e];
#pragma unroll
        for (int k = 0; k < NQB; k++) {
            float t = fminf(fmaxf((float)(k + 1) - u, 0.f), 1.f);  // v_med3
            CN[k] += t;
            CR[k] = fmaf(lfv, t, CR[k]);
        }
    }
#pragma unroll
    for (int k = 0; k < NQB; k++) { CN[k] = red16(CN[k]); CR[k] = red16(CR[k]); }
    if ((l & 15) == 0) {
        int rec = l >> 4;
#pragma unroll
        for (int k = 0; k < NQB; k++) { CNs[q][rec][k] = CN[k]; CRs[q][rec][k] = CR[k]; }
    }
    __syncthreads();

    // ---- AP per query (4 threads), block sum -> 1 float ----
    if (tid < 4) {
        float ap = 0.f, prev = 0.f;
#pragma unroll
        for (int k = 0; k < NQB; k++) {
            float cn = CNs[tid][0][k] + CNs[tid][1][k] + CNs[tid][2][k] + CNs[tid][3][k];
            float cr = CRs[tid][0][k] + CRs[tid][1][k] + CRs[tid][2][k] + CRs[tid][3][k];
            float pr = cr / (1e-16f + cn);
            ap += pr * (cr - prev);
            prev = cr;
        }
        apb[tid] = ap / prev;
    }
    __syncthreads();
    if (tid == 0) appart[blockIdx.x] = apb[0] + apb[1] + apb[2] + apb[3];
}

// ---- K3: final reduce of per-block sums -> d_out ---------------------------
__global__ __launch_bounds__(256) void k_final(const float* __restrict__ appart,
                                               float* __restrict__ out,
                                               int nb, float invn)
{
    int tid = threadIdx.x;
    float v = 0.f;
    for (int i = tid; i < nb; i += 256) v += appart[i];
    for (int off = 32; off; off >>= 1) v += __shfl_xor(v, off, 64);
    __shared__ float wsum[4];
    if ((tid & 63) == 0) wsum[tid >> 6] = v;
    __syncthreads();
    if (tid == 0) out[0] = (wsum[0] + wsum[1] + wsum[2] + wsum[3]) * invn;
}

extern "C" void kernel_launch(void* const* d_in, const int* in_sizes, int n_in,
                              void* d_out, int out_size, void* d_ws, size_t ws_size,
                              hipStream_t stream)
{
    const float* desc1 = (const float*)d_in[0];
    const float* desc2 = (const float*)d_in[1];
    // d_in[2] = reliability: unused by the reference output
    const float* grd   = (const float*)d_in[3];
    const int*   label = (const int*)d_in[4];

    int B = in_sizes[0] / (128 * 1024);
    int npos = B * 1024;

    float* ws = (float*)d_ws;
    float* dbt    = ws;                          // npos*128 floats ([b][c][m])
    float* appart = dbt + (size_t)npos * 128;    // npos/4 floats
    float* out = (float*)d_out;

    k_gs<<<B * 128, 256, 0, stream>>>(desc2, grd, dbt);
    k_main<<<npos / 4, 256, 0, stream>>>(desc1, dbt, label, appart);
    k_final<<<1, 256, 0, stream>>>(appart, out, npos / 4, 1.f / (float)npos);
}